// Round 2
// 570.686 us; speedup vs baseline: 1.0466x; 1.0466x over previous
//
#include <hip/hip_runtime.h>
#include <math.h>

#define B 64
#define L 16384
#define C 64
#define D 256
#define H 100
#define F 320
#define EPSV 1e-12f

typedef float nfloat4 __attribute__((ext_vector_type(4)));

__device__ inline float waveReduceSum(float v) {
    v += __shfl_xor(v, 32);
    v += __shfl_xor(v, 16);
    v += __shfl_xor(v, 8);
    v += __shfl_xor(v, 4);
    v += __shfl_xor(v, 2);
    v += __shfl_xor(v, 1);
    return v;
}

// ---------------- Kernel 1: controller MLP + heads (tiny) ----------------
__global__ __launch_bounds__(128) void head_kernel(
    const float* __restrict__ inputs, const float* __restrict__ reading,
    const float* __restrict__ W1, const float* __restrict__ b1,
    const float* __restrict__ W2, const float* __restrict__ b2,
    const float* __restrict__ Wk_r, const float* __restrict__ bk_r,
    const float* __restrict__ Ws_r, const float* __restrict__ bs_r,
    const float* __restrict__ Wk_w, const float* __restrict__ bk_w,
    const float* __restrict__ Ws_w, const float* __restrict__ bs_w,
    const float* __restrict__ We, const float* __restrict__ be,
    const float* __restrict__ Wa, const float* __restrict__ ba,
    float* __restrict__ kv_r, float* __restrict__ kv_w,
    float* __restrict__ ev, float* __restrict__ av,
    float* __restrict__ s_r, float* __restrict__ s_w)
{
    const int b = blockIdx.x;
    const int t = threadIdx.x;
    __shared__ float feat[F];
    __shared__ float h1[H];
    __shared__ float h2[H];
    __shared__ float kr[C], kw[C], ee[C], aa[C];
    __shared__ float inv_r, inv_w;

    for (int i = t; i < D; i += 128) feat[i] = inputs[b * D + i];
    if (t < C) feat[D + t] = reading[b * C + t];
    __syncthreads();

    if (t < H) {
        float acc = b1[t];
        for (int f = 0; f < F; ++f) acc += feat[f] * W1[f * H + t];
        h1[t] = tanhf(acc);
    }
    __syncthreads();
    if (t < H) {
        float acc = b2[t];
        for (int k = 0; k < H; ++k) acc += h1[k] * W2[k * H + t];
        h2[t] = tanhf(acc);
    }
    __syncthreads();

    if (t < C) {
        float a0 = bk_r[t], a1 = bk_w[t], a2 = be[t], a3 = ba[t];
        for (int j = 0; j < H; ++j) {
            float hv = h2[j];
            a0 += hv * Wk_r[j * C + t];
            a1 += hv * Wk_w[j * C + t];
            a2 += hv * We[j * C + t];
            a3 += hv * Wa[j * C + t];
        }
        kr[t] = a0; kw[t] = a1;
        ee[t] = 1.f / (1.f + expf(-a2));
        aa[t] = 1.f / (1.f + expf(-a3));
    } else if (t == 64 || t == 65) {
        const float* Ws = (t == 64) ? Ws_r : Ws_w;
        float acc = (t == 64) ? bs_r[0] : bs_w[0];
        for (int j = 0; j < H; ++j) acc += h2[j] * Ws[j];
        float s = 1.f / (1.f + expf(-acc));
        if (t == 64) s_r[b] = s; else s_w[b] = s;
    }
    __syncthreads();
    if (t < 64) {
        // wave-parallel norm reduce
        const float xr = kr[t], xw = kw[t];
        const float nr = waveReduceSum(xr * xr);
        const float nw = waveReduceSum(xw * xw);
        if (t == 0) {
            inv_r = 1.f / fmaxf(sqrtf(nr), EPSV);
            inv_w = 1.f / fmaxf(sqrtf(nw), EPSV);
        }
    }
    __syncthreads();
    if (t < C) {
        kv_r[b * C + t] = kr[t] * inv_r;
        kv_w[b * C + t] = kw[t] * inv_w;
        ev[b * C + t] = ee[t];
        av[b * C + t] = aa[t];
    }
}

// ---------------- Kernel 2: pass A over memory (dots + sumsq) ----------------
// Block: 256 threads = 4 waves. Wave handles 4 rows/iter: lane = sub*16 + m,
// each lane loads float4 at column m*4 of row (base + wave*4 + sub).
// Packed reduction: fold pr/pw with xor-1, then carry both (even lanes pr,
// odd lanes pw) through one xor 2/4/8 tree: 6 swizzles instead of 8.
__global__ __launch_bounds__(256) void passA_kernel(
    const float* __restrict__ mem,
    const float* __restrict__ kv_r, const float* __restrict__ kv_w,
    float2* __restrict__ dot2,
    float* __restrict__ sumsq)
{
    const int b = blockIdx.y;
    const int t = threadIdx.x;
    const int wave = t >> 6, lane = t & 63;
    const int sub = lane >> 4, m = lane & 15;

    const float4 kr = *(const float4*)(kv_r + b * C + m * 4);
    const float4 kw = *(const float4*)(kv_w + b * C + m * 4);
    const float4* memv = (const float4*)(mem + (size_t)b * L * C);
    float2* d2 = dot2 + (size_t)b * L;

    float lss = 0.f;
    const int row0 = blockIdx.x * 512;
    #pragma unroll 4
    for (int it = 0; it < 32; ++it) {
        const int row = row0 + it * 16 + wave * 4 + sub;
        const float4 v = memv[row * 16 + m];
        float pr = v.x * kr.x + v.y * kr.y + v.z * kr.z + v.w * kr.w;
        float pw = v.x * kw.x + v.y * kw.y + v.z * kw.z + v.w * kw.w;
        lss += v.x * v.x + v.y * v.y + v.z * v.z + v.w * v.w;
        pr += __shfl_xor(pr, 1);
        pw += __shfl_xor(pw, 1);
        float x = (m & 1) ? pw : pr;
        x += __shfl_xor(x, 2);
        x += __shfl_xor(x, 4);
        x += __shfl_xor(x, 8);
        const float y = __shfl_xor(x, 1);   // at m==0: y = sum(pw)
        if (m == 0) d2[row] = make_float2(x, y);
    }
    lss = waveReduceSum(lss);
    __shared__ float wsum[4];
    if (lane == 0) wsum[wave] = lss;
    __syncthreads();
    if (t == 0) atomicAdd(&sumsq[b], wsum[0] + wsum[1] + wsum[2] + wsum[3]);
}

// ---------------- Kernel 3: softmax stats per (b, head) ----------------
// One block per batch, 1024 threads, single register-resident sweep.
// Emits {scale, max, 1/sum} per head; passB applies exp inline.
__global__ __launch_bounds__(1024) void stats_kernel(
    const float2* __restrict__ dot2,
    const float* __restrict__ s_r, const float* __restrict__ s_w,
    const float* __restrict__ sumsq,
    float* __restrict__ stats)
{
    const int b = blockIdx.x;
    const int t = threadIdx.x;
    const int wave = t >> 6, lane = t & 63;
    const float invn = 1.f / fmaxf(sqrtf(sumsq[b]), EPSV);
    const float sc_r = s_r[b] * invn;
    const float sc_w = s_w[b] * invn;
    const float2* p = dot2 + (size_t)b * L;

    float2 v[16];
    #pragma unroll
    for (int k = 0; k < 16; ++k) v[k] = p[t + k * 1024];

    float mr = -INFINITY, mw = -INFINITY;
    #pragma unroll
    for (int k = 0; k < 16; ++k) {
        mr = fmaxf(mr, v[k].x * sc_r);
        mw = fmaxf(mw, v[k].y * sc_w);
    }
    #pragma unroll
    for (int off = 32; off; off >>= 1) {
        mr = fmaxf(mr, __shfl_xor(mr, off));
        mw = fmaxf(mw, __shfl_xor(mw, off));
    }
    __shared__ float redr[16], redw[16];
    if (lane == 0) { redr[wave] = mr; redw[wave] = mw; }
    __syncthreads();
    if (t == 0) {
        float a = redr[0], c = redw[0];
        for (int i = 1; i < 16; ++i) { a = fmaxf(a, redr[i]); c = fmaxf(c, redw[i]); }
        redr[0] = a; redw[0] = c;
    }
    __syncthreads();
    const float bmr = redr[0], bmw = redw[0];
    __syncthreads();

    float sr = 0.f, sw = 0.f;
    #pragma unroll
    for (int k = 0; k < 16; ++k) {
        sr += expf(v[k].x * sc_r - bmr);
        sw += expf(v[k].y * sc_w - bmw);
    }
    sr = waveReduceSum(sr);
    sw = waveReduceSum(sw);
    if (lane == 0) { redr[wave] = sr; redw[wave] = sw; }
    __syncthreads();
    if (t == 0) {
        float a = 0.f, c = 0.f;
        for (int i = 0; i < 16; ++i) { a += redr[i]; c += redw[i]; }
        float* st = stats + b * 8;
        st[0] = sc_r; st[1] = bmr; st[2] = 1.f / a;
        st[3] = sc_w; st[4] = bmw; st[5] = 1.f / c;
    }
}

// ---------------- Kernel 4: pass B (new_mem write + read-vector) ----------------
__global__ __launch_bounds__(256) void passB_kernel(
    const float* __restrict__ mem,
    const float2* __restrict__ dot2,
    const float* __restrict__ stats,
    const float* __restrict__ ev, const float* __restrict__ av,
    float* __restrict__ out_read, float* __restrict__ new_mem)
{
    const int b = blockIdx.y;
    const int t = threadIdx.x;
    const int wave = t >> 6, lane = t & 63;
    const int sub = lane >> 4, m = lane & 15;

    const float4 e4 = *(const float4*)(ev + b * C + m * 4);
    const float4 a4 = *(const float4*)(av + b * C + m * 4);
    const float* st = stats + b * 8;
    const float sc_r = st[0], mx_r = st[1], inv_r = st[2];
    const float sc_w = st[3], mx_w = st[4], inv_w = st[5];
    const float4* memv = (const float4*)(mem + (size_t)b * L * C);
    nfloat4* outv = (nfloat4*)(new_mem + (size_t)b * L * C);
    const float2* d2 = dot2 + (size_t)b * L;

    float4 racc = {0.f, 0.f, 0.f, 0.f};
    const int row0 = blockIdx.x * 512;
    #pragma unroll 2
    for (int it = 0; it < 32; ++it) {
        const int row = row0 + it * 16 + wave * 4 + sub;
        const float2 d = d2[row];
        const float wr = expf(d.x * sc_r - mx_r) * inv_r;
        const float ww = expf(d.y * sc_w - mx_w) * inv_w;
        const float4 v = memv[row * 16 + m];
        nfloat4 nm;
        nm.x = v.x * (1.f - ww * e4.x) + ww * a4.x;
        nm.y = v.y * (1.f - ww * e4.y) + ww * a4.y;
        nm.z = v.z * (1.f - ww * e4.z) + ww * a4.z;
        nm.w = v.w * (1.f - ww * e4.w) + ww * a4.w;
        // nontemporal: no-allocate write keeps `mem` resident in L3
        __builtin_nontemporal_store(nm, &outv[row * 16 + m]);
        racc.x += wr * v.x; racc.y += wr * v.y;
        racc.z += wr * v.z; racc.w += wr * v.w;
    }
    // fold lanes sharing the same column-quad m (xor 16, 32)
    racc.x += __shfl_xor(racc.x, 16); racc.x += __shfl_xor(racc.x, 32);
    racc.y += __shfl_xor(racc.y, 16); racc.y += __shfl_xor(racc.y, 32);
    racc.z += __shfl_xor(racc.z, 16); racc.z += __shfl_xor(racc.z, 32);
    racc.w += __shfl_xor(racc.w, 16); racc.w += __shfl_xor(racc.w, 32);
    __shared__ float lds[4][64];
    if (lane < 16) {
        lds[wave][m * 4 + 0] = racc.x;
        lds[wave][m * 4 + 1] = racc.y;
        lds[wave][m * 4 + 2] = racc.z;
        lds[wave][m * 4 + 3] = racc.w;
    }
    __syncthreads();
    if (t < 64) {
        float tot = lds[0][t] + lds[1][t] + lds[2][t] + lds[3][t];
        atomicAdd(&out_read[b * C + t], tot);
    }
}

extern "C" void kernel_launch(void* const* d_in, const int* in_sizes, int n_in,
                              void* d_out, int out_size, void* d_ws, size_t ws_size,
                              hipStream_t stream) {
    const float* inputs  = (const float*)d_in[0];
    const float* reading = (const float*)d_in[1];
    const float* memory  = (const float*)d_in[2];
    const float* W1 = (const float*)d_in[3];
    const float* b1 = (const float*)d_in[4];
    const float* W2 = (const float*)d_in[5];
    const float* b2 = (const float*)d_in[6];
    const float* Wk_r = (const float*)d_in[7];
    const float* bk_r = (const float*)d_in[8];
    const float* Ws_r = (const float*)d_in[9];
    const float* bs_r = (const float*)d_in[10];
    const float* Wk_w = (const float*)d_in[11];
    const float* bk_w = (const float*)d_in[12];
    const float* Ws_w = (const float*)d_in[13];
    const float* bs_w = (const float*)d_in[14];
    const float* We = (const float*)d_in[15];
    const float* be = (const float*)d_in[16];
    const float* Wa = (const float*)d_in[17];
    const float* ba = (const float*)d_in[18];

    float* ws = (float*)d_ws;
    float* kv_r  = ws;                 // B*C
    float* kv_w  = ws + 4096;          // B*C
    float* ev    = ws + 8192;          // B*C
    float* av    = ws + 12288;         // B*C
    float* s_r   = ws + 16384;         // B
    float* s_w   = ws + 16448;         // B
    float* sumsq = ws + 16512;         // B
    float* stats = ws + 16576;         // B*8
    float* dot2f = ws + 17408;         // B*L*2 (16B-aligned)

    float* out = (float*)d_out;
    float* out_read = out;             // B*C
    float* new_mem  = out + 4096;      // B*L*C  (offset 16 KiB: float4-aligned)

    hipMemsetAsync(sumsq, 0, B * sizeof(float), stream);
    hipMemsetAsync(out_read, 0, B * C * sizeof(float), stream);

    head_kernel<<<B, 128, 0, stream>>>(
        inputs, reading, W1, b1, W2, b2, Wk_r, bk_r, Ws_r, bs_r,
        Wk_w, bk_w, Ws_w, bs_w, We, be, Wa, ba,
        kv_r, kv_w, ev, av, s_r, s_w);

    passA_kernel<<<dim3(32, B), 256, 0, stream>>>(
        memory, kv_r, kv_w, (float2*)dot2f, sumsq);

    stats_kernel<<<B, 1024, 0, stream>>>(
        (const float2*)dot2f, s_r, s_w, sumsq, stats);

    passB_kernel<<<dim3(32, B), 256, 0, stream>>>(
        memory, (const float2*)dot2f, stats, ev, av, out_read, new_mem);
}